// Round 7
// baseline (1252.318 us; speedup 1.0000x reference)
//
#include <hip/hip_runtime.h>

#define N_DRUG 20000
#define N_PROT 8000
#define D_DRUG 300
#define D_PROT 1280
#define HIDDEN 512
#define OUT_D  5
#define N_EDGE 500000
#define N_LBL  200000
#define WLD    812        // W_lin leading dim (300+512)
#define CAP    128        // bucket capacity (deg ~ 62.5 +- 7.9; ~8 sigma)
#define OVF_MAX 65536     // exact overflow list (never expected to fill)
#define NBLK   768        // grid: co-resident guaranteed (launch_bounds 256,4 -> >=1024 cap)
#define NTHR   256
#define SBLK   128        // blocks [0,SBLK) = scatter role in phase 1

// Sense-reversing grid barrier. Device-scope atomics + threadfence so normal
// stores from phase N are visible to normal loads in phase N+1 across XCDs
// (per-XCD L2s are not coherent without these fences).
__device__ __forceinline__ void gbar(unsigned* arrive, unsigned* gen) {
    __threadfence();          // release: push my writes to coherence point
    __syncthreads();
    if (threadIdx.x == 0) {
        unsigned g = __hip_atomic_load(gen, __ATOMIC_ACQUIRE, __HIP_MEMORY_SCOPE_AGENT);
        unsigned a = __hip_atomic_fetch_add(arrive, 1u, __ATOMIC_ACQ_REL, __HIP_MEMORY_SCOPE_AGENT);
        if (a == NBLK - 1u) {
            __hip_atomic_store(arrive, 0u, __ATOMIC_RELAXED, __HIP_MEMORY_SCOPE_AGENT);
            __hip_atomic_fetch_add(gen, 1u, __ATOMIC_ACQ_REL, __HIP_MEMORY_SCOPE_AGENT);
        } else {
            while (__hip_atomic_load(gen, __ATOMIC_ACQUIRE, __HIP_MEMORY_SCOPE_AGENT) == g) {}
        }
    }
    __syncthreads();
    __threadfence();          // acquire: invalidate stale cached lines
}

__global__ __launch_bounds__(NTHR, 4) void k_fused(
        const float* __restrict__ x_drug, const float* __restrict__ x_prot,
        const int* __restrict__ edge_src, const int* __restrict__ edge_dst,
        const int* __restrict__ lbl_src, const int* __restrict__ lbl_dst,
        const float* __restrict__ W_l, const float* __restrict__ b_l,
        const float* __restrict__ W_r, const float* __restrict__ W_lin,
        const float* __restrict__ b_lin,
        unsigned* __restrict__ bar,              // [0]=arrive [1]=gen (memset 0)
        int* __restrict__ cnt, int* __restrict__ novf,
        float* __restrict__ A, float* __restrict__ B, float* __restrict__ c,
        float* __restrict__ P_A, float* __restrict__ drugO, float* __restrict__ protO,
        int* __restrict__ bucket, int* __restrict__ ovf,
        float* __restrict__ out) {
    const int b   = blockIdx.x;
    const int tid = threadIdx.x;
    const int gtid = b * NTHR + tid;

    // ---------- Phase 0: fold weights (non-atomic) + zero cnt/novf ----------
    {
        const int nA = OUT_D * D_DRUG;            // 1500
        const int nB = OUT_D * D_PROT;            // 6400
        int t = gtid;
        if (t < nA) {
            int o = t / D_DRUG, k = t - o * D_DRUG;
            const float* wp = W_lin + o * WLD + D_DRUG;
            const float* wl = W_l + k;
            float s = 0.f;
#pragma unroll 8
            for (int h = 0; h < HIDDEN; ++h) s += wp[h] * wl[(size_t)h * D_DRUG];
            A[t] = s;
        } else if (t < nA + nB) {
            int u = t - nA;
            int o = u / D_PROT, k = u - o * D_PROT;
            const float* wp = W_lin + o * WLD + D_DRUG;
            const float* wr = W_r + k;
            float s = 0.f;
#pragma unroll 8
            for (int h = 0; h < HIDDEN; ++h) s += wp[h] * wr[(size_t)h * D_PROT];
            B[u] = s;
        } else if (t < nA + nB + OUT_D) {
            int o = t - nA - nB;
            const float* wp = W_lin + o * WLD + D_DRUG;
            float s = 0.f;
            for (int h = 0; h < HIDDEN; ++h) s += wp[h] * b_l[h];
            c[o] = s;
        } else if (t >= 8192 && t < 8192 + N_PROT + 1) {
            int z = t - 8192;
            if (z < N_PROT) cnt[z] = 0; else *novf = 0;
        }
    }
    gbar(&bar[0], &bar[1]);

    // ---------- Phase 1: scatter (blocks [0,SBLK)) || GEMMs (rest) ----------
    if (b < SBLK) {
        for (int e = b * NTHR + tid; e < N_EDGE; e += SBLK * NTHR) {
            int s = edge_src[e], d = edge_dst[e];
            int r = atomicAdd(&cnt[d], 1);
            if (r < CAP) {
                bucket[d * CAP + r] = s;
            } else {
                int o = atomicAdd(novf, 1);
                if (o < OVF_MAX) { ovf[2 * o] = d; ovf[2 * o + 1] = s; }
            }
        }
    } else {
        // 3250 work units: [0,1250) drug (16 rows x 16 lanes), [1250,3250) prot (4 rows x 64 lanes)
        for (int u = b - SBLK; u < 3250; u += NBLK - SBLK) {
            if (u < 1250) {
                int row = u * 16 + (tid >> 4);
                int sub = tid & 15;
                const float4* xr = (const float4*)(x_drug + (size_t)row * D_DRUG);  // 75 float4
                float acc[10];
#pragma unroll
                for (int i = 0; i < 10; ++i) acc[i] = 0.f;
                for (int k = sub; k < D_DRUG / 4; k += 16) {
                    float4 x = xr[k];
#pragma unroll
                    for (int o = 0; o < OUT_D; ++o) {
                        float4 a = ((const float4*)(A + o * D_DRUG))[k];
                        acc[o] += x.x * a.x + x.y * a.y + x.z * a.z + x.w * a.w;
                        float4 w = ((const float4*)(W_lin + o * WLD))[k];
                        acc[5 + o] += x.x * w.x + x.y * w.y + x.z * w.z + x.w * w.w;
                    }
                }
#pragma unroll
                for (int i = 0; i < 10; ++i) {
                    float v = acc[i];
                    for (int m = 8; m; m >>= 1) v += __shfl_xor(v, m, 64);
                    acc[i] = v;
                }
                if (sub < OUT_D) {
                    P_A[row * OUT_D + sub]   = acc[sub];
                    drugO[row * OUT_D + sub] = acc[5 + sub];
                }
            } else {
                int pu   = u - 1250;
                int row  = pu * 4 + (tid >> 6);
                int lane = tid & 63;
                const float4* xr = (const float4*)(x_prot + (size_t)row * D_PROT);  // 320 float4
                float acc[OUT_D] = {0.f, 0.f, 0.f, 0.f, 0.f};
                for (int k = lane; k < D_PROT / 4; k += 64) {
                    float4 x = xr[k];
#pragma unroll
                    for (int o = 0; o < OUT_D; ++o) {
                        float4 bb = ((const float4*)(B + o * D_PROT))[k];
                        acc[o] += x.x * bb.x + x.y * bb.y + x.z * bb.z + x.w * bb.w;
                    }
                }
#pragma unroll
                for (int o = 0; o < OUT_D; ++o) {
                    float v = acc[o];
                    for (int off = 32; off; off >>= 1) v += __shfl_xor(v, off, 64);
                    acc[o] = v;
                }
                if (lane < OUT_D) protO[row * OUT_D + lane] = acc[lane] + c[lane];
            }
        }
    }
    gbar(&bar[0], &bar[1]);

    // ---------- Phase 2: bucket gather-mean into protO ----------
    {
        const int nwaves = NBLK * NTHR / 64;   // 3072
        int lane = tid & 63;
        for (int row = gtid >> 6; row < N_PROT; row += nwaves) {
            int deg = cnt[row];
            int m = deg < CAP ? deg : CAP;
            float acc[OUT_D] = {0.f, 0.f, 0.f, 0.f, 0.f};
            const int* br = &bucket[row * CAP];
            for (int j = lane; j < m; j += 64) {
                const float* p = &P_A[br[j] * OUT_D];
#pragma unroll
                for (int o = 0; o < OUT_D; ++o) acc[o] += p[o];
            }
            if (deg > CAP) {   // exact tail via overflow list
                int nv = *novf; if (nv > OVF_MAX) nv = OVF_MAX;
                for (int j = lane; j < nv; j += 64) {
                    if (ovf[2 * j] == row) {
                        const float* p = &P_A[ovf[2 * j + 1] * OUT_D];
#pragma unroll
                        for (int o = 0; o < OUT_D; ++o) acc[o] += p[o];
                    }
                }
            }
#pragma unroll
            for (int o = 0; o < OUT_D; ++o) {
                float v = acc[o];
                for (int off = 32; off; off >>= 1) v += __shfl_xor(v, off, 64);
                acc[o] = v;
            }
            if (lane < OUT_D)
                protO[row * OUT_D + lane] += acc[lane] / fmaxf((float)deg, 1.f);
        }
    }
    gbar(&bar[0], &bar[1]);

    // ---------- Phase 3: final gather-add ----------
    {
        float bl[OUT_D];
#pragma unroll
        for (int o = 0; o < OUT_D; ++o) bl[o] = b_lin[o];
        for (int l = gtid; l < N_LBL; l += NBLK * NTHR) {
            int s = lbl_src[l], d = lbl_dst[l];
            const float* dr = &drugO[s * OUT_D];
            const float* pr = &protO[d * OUT_D];
            float* op = &out[(size_t)l * OUT_D];
            op[0] = dr[0] + pr[0] + bl[0];
            op[1] = dr[1] + pr[1] + bl[1];
            op[2] = dr[2] + pr[2] + bl[2];
            op[3] = dr[3] + pr[3] + bl[3];
            op[4] = dr[4] + pr[4] + bl[4];
        }
    }
}

extern "C" void kernel_launch(void* const* d_in, const int* in_sizes, int n_in,
                              void* d_out, int out_size, void* d_ws, size_t ws_size,
                              hipStream_t stream) {
    const float* x_drug   = (const float*)d_in[0];
    const float* x_prot   = (const float*)d_in[1];
    const int*   edge_src = (const int*)d_in[2];
    const int*   edge_dst = (const int*)d_in[3];
    const int*   lbl_src  = (const int*)d_in[4];
    const int*   lbl_dst  = (const int*)d_in[5];
    const float* W_l      = (const float*)d_in[6];
    const float* b_l      = (const float*)d_in[7];
    const float* W_r      = (const float*)d_in[8];
    const float* W_lin    = (const float*)d_in[9];
    const float* b_lin    = (const float*)d_in[10];
    float* out = (float*)d_out;

    // workspace layout; only [0,64) needs host-side zeroing (barrier state);
    // cnt/novf are zeroed in-kernel (phase 0); A/B/c are written non-atomically.
    char* ws = (char*)d_ws;
    unsigned* bar  = (unsigned*)(ws + 0);      //     64 B  [memset 0]
    int*   cnt     = (int*)  (ws + 64);        //  32000 B (zeroed in P0)
    int*   novf    = (int*)  (ws + 32064);     //      4 B (zeroed in P0)
    float* A       = (float*)(ws + 32128);     //   6000 B
    float* B       = (float*)(ws + 38144);     //  25600 B
    float* c       = (float*)(ws + 63744);     //     20 B
    float* P_A     = (float*)(ws + 64000);     // 400000 B
    float* drugO   = (float*)(ws + 464000);    // 400000 B
    float* protO   = (float*)(ws + 864000);    // 160000 B
    int*   bucket  = (int*)  (ws + 1024000);   // 4096000 B (8000 x 128)
    int*   ovf     = (int*)  (ws + 5120000);   // 524288 B
    // total: 5,644,288 B

    hipMemsetAsync(ws, 0, 64, stream);
    k_fused<<<NBLK, NTHR, 0, stream>>>(
        x_drug, x_prot, edge_src, edge_dst, lbl_src, lbl_dst,
        W_l, b_l, W_r, W_lin, b_lin,
        bar, cnt, novf, A, B, c, P_A, drugO, protO, bucket, ovf, out);
}

// Round 8
// 169.321 us; speedup vs baseline: 7.3961x; 7.3961x over previous
//
#include <hip/hip_runtime.h>

#define N_DRUG 20000
#define N_PROT 8000
#define D_DRUG 300
#define D_PROT 1280
#define HIDDEN 512
#define OUT_D  5
#define N_EDGE 500000
#define N_LBL  200000
#define WLD    812        // W_lin leading dim (300+512)
#define CAP    128        // bucket capacity (deg ~ 62.5 +- 7.9; ~8 sigma)
#define OVF_MAX 65536     // exact overflow list (never expected to fill)
#define SBLK   128        // scatter blocks in D2

// =========================================================================
// D1: folded weights only (h-split 8x, atomic partials onto zeroed A/B/c)
//   A[o,k] = sum_h W_lin[o,300+h] * W_l[h,k]   (5 x 300)
//   B[o,k] = sum_h W_lin[o,300+h] * W_r[h,k]   (5 x 1280)
//   c[o]   = sum_h W_lin[o,300+h] * b_l[h]     (5)
// =========================================================================
__global__ void k_fold(const float* __restrict__ W_l, const float* __restrict__ W_r,
                       const float* __restrict__ W_lin, const float* __restrict__ b_l,
                       float* __restrict__ A, float* __restrict__ B, float* __restrict__ c) {
    int t  = (blockIdx.x % 31) * 256 + threadIdx.x;
    int h0 = (blockIdx.x / 31) * 64;
    const int nA = OUT_D * D_DRUG;   // 1500
    const int nB = OUT_D * D_PROT;   // 6400
    if (t < nA) {
        int o = t / D_DRUG, k = t - o * D_DRUG;
        const float* wp = W_lin + o * WLD + D_DRUG + h0;
        const float* wl = W_l + (size_t)h0 * D_DRUG + k;
        float s = 0.f;
#pragma unroll 4
        for (int h = 0; h < 64; ++h) s += wp[h] * wl[h * D_DRUG];
        atomicAdd(&A[t], s);
    } else if (t < nA + nB) {
        int u = t - nA;
        int o = u / D_PROT, k = u - o * D_PROT;
        const float* wp = W_lin + o * WLD + D_DRUG + h0;
        const float* wr = W_r + (size_t)h0 * D_PROT + k;
        float s = 0.f;
#pragma unroll 4
        for (int h = 0; h < 64; ++h) s += wp[h] * wr[h * D_PROT];
        atomicAdd(&B[u], s);
    } else if (t < nA + nB + OUT_D) {
        int o = t - nA - nB;
        const float* wp = W_lin + o * WLD + D_DRUG + h0;
        float s = 0.f;
        for (int h = 0; h < 64; ++h) s += wp[h] * b_l[h0 + h];
        atomicAdd(&c[o], s);
    }
}

// =========================================================================
// D2: scatter || both dense GEMMs, block-specialized (no internal deps:
// scatter touches cnt/bucket/ovf; GEMMs read A/B/c from D1, write P_A/
// drugO/protO). Scatter blocks dispatch first and own the atomic pipe;
// the HBM-bound GEMM stream hides under the ~25us atomic wall.
//   blocks [0,128):      bucketed edge scatter (grid-stride)
//   blocks [128,1378):   drug rows: P_A = x_drug@A.T, drugO = x_drug@Wlin_d.T
//   blocks [1378,3378):  prot rows: protO = x_prot@B.T + c
// =========================================================================
__global__ void k_mid(const float* __restrict__ x_drug, const float* __restrict__ x_prot,
                      const int* __restrict__ edge_src, const int* __restrict__ edge_dst,
                      const float* __restrict__ A, const float* __restrict__ B,
                      const float* __restrict__ c, const float* __restrict__ W_lin,
                      int* __restrict__ cnt, int* __restrict__ novf,
                      int* __restrict__ bucket, int* __restrict__ ovf,
                      float* __restrict__ P_A, float* __restrict__ drugO,
                      float* __restrict__ protO) {
    int b = blockIdx.x;
    int tid = threadIdx.x;
    if (b < SBLK) {
        // ---- bucketed scatter: r = cnt[d]++; bucket[d*CAP+r] = s ----
        for (int e = b * 256 + tid; e < N_EDGE; e += SBLK * 256) {
            int s = edge_src[e], d = edge_dst[e];
            int r = atomicAdd(&cnt[d], 1);
            if (r < CAP) {
                bucket[d * CAP + r] = s;
            } else {    // exact overflow list (input-only fallback)
                int o = atomicAdd(novf, 1);
                if (o < OVF_MAX) { ovf[2 * o] = d; ovf[2 * o + 1] = s; }
            }
        }
    } else if (b < SBLK + 1250) {
        // ---- drug rows: 16 rows/block x 16 lanes/row ----
        int row = (b - SBLK) * 16 + (tid >> 4);
        int sub = tid & 15;
        const float4* xr = (const float4*)(x_drug + (size_t)row * D_DRUG);  // 75 float4
        float acc[10];
#pragma unroll
        for (int i = 0; i < 10; ++i) acc[i] = 0.f;
        for (int k = sub; k < D_DRUG / 4; k += 16) {
            float4 x = xr[k];
#pragma unroll
            for (int o = 0; o < OUT_D; ++o) {
                float4 a = ((const float4*)(A + o * D_DRUG))[k];
                acc[o] += x.x * a.x + x.y * a.y + x.z * a.z + x.w * a.w;
                float4 w = ((const float4*)(W_lin + o * WLD))[k];
                acc[5 + o] += x.x * w.x + x.y * w.y + x.z * w.z + x.w * w.w;
            }
        }
#pragma unroll
        for (int i = 0; i < 10; ++i) {
            float v = acc[i];
            for (int m = 8; m; m >>= 1) v += __shfl_xor(v, m, 64);
            acc[i] = v;
        }
        if (sub < OUT_D) {
            P_A[row * OUT_D + sub]   = acc[sub];
            drugO[row * OUT_D + sub] = acc[5 + sub];
        }
    } else {
        // ---- prot rows: 4 rows/block x 64 lanes/row ----
        int row  = (b - SBLK - 1250) * 4 + (tid >> 6);
        int lane = tid & 63;
        const float4* xr = (const float4*)(x_prot + (size_t)row * D_PROT);  // 320 float4
        float acc[OUT_D] = {0.f, 0.f, 0.f, 0.f, 0.f};
        for (int k = lane; k < D_PROT / 4; k += 64) {
            float4 x = xr[k];
#pragma unroll
            for (int o = 0; o < OUT_D; ++o) {
                float4 bb = ((const float4*)(B + o * D_PROT))[k];
                acc[o] += x.x * bb.x + x.y * bb.y + x.z * bb.z + x.w * bb.w;
            }
        }
#pragma unroll
        for (int o = 0; o < OUT_D; ++o) {
            float v = acc[o];
            for (int off = 32; off; off >>= 1) v += __shfl_xor(v, off, 64);
            acc[o] = v;
        }
        if (lane < OUT_D) protO[row * OUT_D + lane] = acc[lane] + c[lane];
    }
}

// =========================================================================
// D3: bucket gather-mean, added into protO (one wave per protein)
// =========================================================================
__global__ void k_gather(const int* __restrict__ cnt, const int* __restrict__ novf,
                         const int* __restrict__ bucket, const int* __restrict__ ovf,
                         const float* __restrict__ P_A, float* __restrict__ protO) {
    int wave = (blockIdx.x * blockDim.x + threadIdx.x) >> 6;
    int lane = threadIdx.x & 63;
    if (wave >= N_PROT) return;
    int deg = cnt[wave];
    int m = deg < CAP ? deg : CAP;
    float acc[OUT_D] = {0.f, 0.f, 0.f, 0.f, 0.f};
    const int* br = &bucket[wave * CAP];
    for (int j = lane; j < m; j += 64) {
        const float* p = &P_A[br[j] * OUT_D];
#pragma unroll
        for (int o = 0; o < OUT_D; ++o) acc[o] += p[o];
    }
    if (deg > CAP) {   // exact tail via overflow list
        int nv = *novf; if (nv > OVF_MAX) nv = OVF_MAX;
        for (int j = lane; j < nv; j += 64) {
            if (ovf[2 * j] == wave) {
                const float* p = &P_A[ovf[2 * j + 1] * OUT_D];
#pragma unroll
                for (int o = 0; o < OUT_D; ++o) acc[o] += p[o];
            }
        }
    }
#pragma unroll
    for (int o = 0; o < OUT_D; ++o) {
        float v = acc[o];
        for (int off = 32; off; off >>= 1) v += __shfl_xor(v, off, 64);
        acc[o] = v;
    }
    if (lane < OUT_D)
        protO[wave * OUT_D + lane] += acc[lane] / fmaxf((float)deg, 1.f);
}

// =========================================================================
// D4: final gather-add
// =========================================================================
__global__ void k_final(const int* __restrict__ lbl_src, const int* __restrict__ lbl_dst,
                        const float* __restrict__ drugO, const float* __restrict__ protO,
                        const float* __restrict__ b_lin, float* __restrict__ out) {
    int l = blockIdx.x * blockDim.x + threadIdx.x;
    if (l >= N_LBL) return;
    int s = lbl_src[l], d = lbl_dst[l];
    const float* dr = &drugO[s * OUT_D];
    const float* pr = &protO[d * OUT_D];
    float* op = &out[(size_t)l * OUT_D];
    op[0] = dr[0] + pr[0] + b_lin[0];
    op[1] = dr[1] + pr[1] + b_lin[1];
    op[2] = dr[2] + pr[2] + b_lin[2];
    op[3] = dr[3] + pr[3] + b_lin[3];
    op[4] = dr[4] + pr[4] + b_lin[4];
}

extern "C" void kernel_launch(void* const* d_in, const int* in_sizes, int n_in,
                              void* d_out, int out_size, void* d_ws, size_t ws_size,
                              hipStream_t stream) {
    const float* x_drug   = (const float*)d_in[0];
    const float* x_prot   = (const float*)d_in[1];
    const int*   edge_src = (const int*)d_in[2];
    const int*   edge_dst = (const int*)d_in[3];
    const int*   lbl_src  = (const int*)d_in[4];
    const int*   lbl_dst  = (const int*)d_in[5];
    const float* W_l      = (const float*)d_in[6];
    const float* b_l      = (const float*)d_in[7];
    const float* W_r      = (const float*)d_in[8];
    const float* W_lin    = (const float*)d_in[9];
    const float* b_lin    = (const float*)d_in[10];
    float* out = (float*)d_out;

    // workspace layout; [0, 63648) zeroed by the single memset
    char* ws = (char*)d_ws;
    int*   cnt    = (int*)  (ws + 0);          //  32000 B (8000)     [zeroed]
    int*   novf   = (int*)  (ws + 32000);      //     16 B           [zeroed]
    float* A      = (float*)(ws + 32016);      //   6000 B (5x300)   [zeroed]
    float* B      = (float*)(ws + 38016);      //  25600 B (5x1280)  [zeroed]
    float* c      = (float*)(ws + 63616);      //     20 B           [zeroed]
    float* P_A    = (float*)(ws + 64000);      // 400000 B
    float* drugO  = (float*)(ws + 464000);     // 400000 B
    float* protO  = (float*)(ws + 864000);     // 160000 B
    int*   bucket = (int*)  (ws + 1024000);    // 4096000 B (8000 x 128)
    int*   ovf    = (int*)  (ws + 5120000);    // 524288 B (65536 pairs)
    // total: 5,644,288 B

    hipMemsetAsync(ws, 0, 63648, stream);
    k_fold<<<248, 256, 0, stream>>>(W_l, W_r, W_lin, b_l, A, B, c);
    k_mid<<<SBLK + 1250 + 2000, 256, 0, stream>>>(
        x_drug, x_prot, edge_src, edge_dst, A, B, c, W_lin,
        cnt, novf, bucket, ovf, P_A, drugO, protO);
    k_gather<<<(N_PROT * 64) / 256, 256, 0, stream>>>(cnt, novf, bucket, ovf, P_A, protO);
    k_final<<<(N_LBL + 255) / 256, 256, 0, stream>>>(lbl_src, lbl_dst, drugO, protO, b_lin, out);
}